// Round 13
// baseline (51.783 us; speedup 1.0000x reference)
//
#include <hip/hip_runtime.h>

#define P   7
#define GS  7
#define D   21
#define HH  80
#define WW  80
#define CC  (D * GS * GS)        // 1029
#define PLANE (HH * WW)          // 6400 floats
#define IW  84                   // row stride: rows = 21 x 16B chunks exactly
#define NSEG 5
#define SEGLEN 16
#define NBLK 512                 // 2 blocks/CU exactly
#define BUFQ 2048                // padded chunk count (uniform 4 gll/thread-slot)
#define BUFF (BUFQ * 4)          // 8192 floats per buffer (32 KB)
#define REALQ 1680               // real chunks: 80 rows * 21

// fl32(1/7) = 0x3E124925 — the golden divides via reciprocal multiply.
__device__ __forceinline__ float recip7() {
    union { unsigned u; float f; } c; c.u = 0x3E124925u; return c.f;
}

// a*b + c with a HARD barrier between mul and add: no fma contraction ever.
__device__ __forceinline__ float mul_add_nofma(float a, float b, float c) {
    float t = a * b;
    asm volatile("" : "+v"(t));
    return t + c;
}

#define MEMFENCE() asm volatile("" ::: "memory")
// lgkmcnt(0) + raw barrier + fence: own LDS ops visible, no motion across.
#define LGKM_BAR() do { asm volatile("s_waitcnt lgkmcnt(0)" ::: "memory"); \
                        __builtin_amdgcn_s_barrier(); MEMFENCE(); } while (0)

__device__ __forceinline__ void gll16(const float* g, float* l) {
    __builtin_amdgcn_global_load_lds(
        (const __attribute__((address_space(1))) void*)g,
        (__attribute__((address_space(3))) void*)l, 16, 0, 0);
}

// Issue exactly 4 gll per thread-slot (uniform per wave) staging one plane
// into buf with the [80][84] layout (row = 21 chunks of 16B, chunk 20 = pad).
__device__ __forceinline__ void stage_issue(const float* plane, float* buf, int tid) {
    #pragma unroll
    for (int k = 0; k < 4; ++k) {
        int q0 = (tid & ~63) + k * 512;        // wave-uniform chunk base
        int q  = q0 + (tid & 63);
        int row = q / 21, w4 = q - row * 21;
        const float* src = (q < REALQ && w4 < 20) ? (plane + row * WW + w4 * 4)
                                                  : plane;   // pad/dummy: junk, never read
        gll16(src, buf + q0 * 4);              // HW adds lane*16B
    }
}

// ---------- prep: edges + parallel 2-level ballot compaction, one block -----
__global__ __launch_bounds__(1024) void prep_kernel(
    const float* __restrict__ rois, int R, int N,
    unsigned short* __restrict__ hshe,
    unsigned short* __restrict__ wswe,
    int* __restrict__ jlist, int* __restrict__ base)
{
    __shared__ unsigned char bsh[2048];
    __shared__ int wcnt[16][8];
    __shared__ int wbase[16][8];
    __shared__ int baseS[9];
    int tid = threadIdx.x, wave = tid >> 6, lane = tid & 63;

    for (int r = tid; r < R; r += 1024) {
        const float* roi = rois + (size_t)r * 5;
        bsh[r] = (unsigned char)(int)roi[0];

        float x1 = rintf(roi[1]) * 0.0625f;
        float y1 = rintf(roi[2]) * 0.0625f;
        float x2 = (rintf(roi[3]) + 1.0f) * 0.0625f;
        float y2 = (rintf(roi[4]) + 1.0f) * 0.0625f;
        float bin_w = fmaxf(x2 - x1, 0.1f) * recip7();
        float bin_h = fmaxf(y2 - y1, 0.1f) * recip7();
        asm volatile("" : "+v"(bin_w), "+v"(bin_h));

        #pragma unroll
        for (int g = 0; g < 7; ++g) {
            float hs_f = floorf(mul_add_nofma((float)g,       bin_h, y1));
            float he_f = ceilf (mul_add_nofma((float)(g + 1), bin_h, y1));
            float ws_f = floorf(mul_add_nofma((float)g,       bin_w, x1));
            float we_f = ceilf (mul_add_nofma((float)(g + 1), bin_w, x1));
            int hs = (int)fminf(fmaxf(hs_f, 0.0f), 80.0f);
            int he = (int)fminf(fmaxf(he_f, 0.0f), 80.0f);
            int ws = (int)fminf(fmaxf(ws_f, 0.0f), 80.0f);
            int we = (int)fminf(fmaxf(we_f, 0.0f), 80.0f);
            hshe[r * 7 + g] = (unsigned short)(hs | (he << 8));
            wswe[r * 7 + g] = (unsigned short)(ws | (we << 8));
        }
    }
    __syncthreads();

    int chunk = (R + 15) / 16;
    int rbeg = wave * chunk;
    int rend = min(rbeg + chunk, R);
    int cnt[8];
    #pragma unroll
    for (int b = 0; b < 8; ++b) cnt[b] = 0;
    for (int rr = rbeg + lane; rr < rend; rr += 64) {
        int bv = bsh[rr];
        #pragma unroll
        for (int b = 0; b < 8; ++b) {
            if (b < N) cnt[b] += __popcll(__ballot(bv == b));
        }
    }
    if (lane == 0) {
        #pragma unroll
        for (int b = 0; b < 8; ++b) wcnt[wave][b] = cnt[b];
    }
    __syncthreads();

    if (tid < 8) {
        int b = tid, acc = 0;
        for (int w = 0; w < 16; ++w) { wbase[w][b] = acc; acc += wcnt[w][b]; }
        baseS[b] = acc;
    }
    __syncthreads();
    if (tid == 0) {
        int acc = 0;
        for (int b = 0; b < N; ++b) { int t = baseS[b]; baseS[b] = acc; acc += t; }
        baseS[N] = acc;
    }
    __syncthreads();

    {
        int off[8];
        #pragma unroll
        for (int b = 0; b < 8; ++b) off[b] = (b < N) ? (baseS[b] + wbase[wave][b]) : 0;
        for (int rr = rbeg + lane; rr < rend; rr += 64) {
            int bv = bsh[rr];
            #pragma unroll
            for (int b = 0; b < 8; ++b) {
                if (b < N) {
                    unsigned long long mask = __ballot(bv == b);
                    if (bv == b) {
                        int pos = off[b] + __popcll(mask & ((1ull << lane) - 1ull));
                        jlist[pos] = rr;
                    }
                    off[b] += __popcll(mask);
                }
            }
        }
    }
    if (tid <= N) base[tid] = baseS[tid];
}

// ---------- plane kernel: persistent, double-buffered, counted-vmcnt --------
__global__ __launch_bounds__(512) void psroi_plane_kernel(
    const float* __restrict__ feat, int R, int NPLANES,
    const unsigned short* __restrict__ hshe,
    const unsigned short* __restrict__ wswe,
    const int* __restrict__ jlist, const int* __restrict__ base,
    float* __restrict__ dst)          // ws_T[c][j], j = compacted index
{
    __shared__ float bufA[BUFF];      // 32 KB
    __shared__ float bufB[BUFF];      // 32 KB
    __shared__ float tot[NSEG][HH];   // 1.6 KB

    int tid = threadIdx.x;
    int bid = blockIdx.x;

    // prologue: stage first plane into bufA
    stage_issue(feat + (size_t)bid * PLANE, bufA, tid);

    bool act = tid < NSEG * WW;
    int seg = tid / WW;                // 0..4
    int lw  = tid % WW;                // 0..79

    int parity = 0;
    for (int p = bid; p < NPLANES; p += NBLK, parity ^= 1) {
        float* ii = parity ? bufB : bufA;
        float* nx = parity ? bufA : bufB;
        int pn = p + NBLK;
        if (pn < NPLANES) {
            stage_issue(feat + (size_t)pn * PLANE, nx, tid);
            asm volatile("s_waitcnt vmcnt(4)" ::: "memory");   // cur done, next in flight
        } else {
            asm volatile("s_waitcnt vmcnt(0)" ::: "memory");
        }
        __builtin_amdgcn_s_barrier();
        MEMFENCE();

        // ---- per-plane indices + early table prefetch (overlap cumsums) ----
        int b = p / CC, c = p % CC;
        int rem = c % (GS * GS);
        int gh  = rem / GS, gw = rem % GS;
        int j0 = base[b], j1 = base[b + 1];
        int jA = j0 + tid, jB = jA + 512, jC = jA + 1024, jD = jA + 1536;
        int rA = (jA < j1) ? jlist[jA] : 0;
        int rB = (jB < j1) ? jlist[jB] : 0;
        int rC = (jC < j1) ? jlist[jC] : 0;
        int rD = (jD < j1) ? jlist[jD] : 0;
        unsigned hA = (jA < j1) ? hshe[rA * 7 + gh] : 0;
        unsigned wA = (jA < j1) ? wswe[rA * 7 + gw] : 0;
        unsigned hB = (jB < j1) ? hshe[rB * 7 + gh] : 0;
        unsigned wB = (jB < j1) ? wswe[rB * 7 + gw] : 0;
        unsigned hC = (jC < j1) ? hshe[rC * 7 + gh] : 0;
        unsigned wC = (jC < j1) ? wswe[rC * 7 + gw] : 0;
        unsigned hD = (jD < j1) ? hshe[rD * 7 + gh] : 0;
        unsigned wD = (jD < j1) ? wswe[rD * 7 + gw] : 0;

        // ---- H cumsum (axis=2 first, as golden): b32, register carry ----
        {
            float v[SEGLEN];
            int col = lw, h0 = seg * SEGLEN;
            if (act) {
                float s = 0.0f;
                #pragma unroll
                for (int k = 0; k < SEGLEN; ++k) { v[k] = ii[(h0 + k) * IW + col]; s += v[k]; }
                tot[seg][lw] = s;
            }
            LGKM_BAR();
            if (act) {
                float off = 0.0f;
                #pragma unroll
                for (int jj = 0; jj < NSEG - 1; ++jj) if (jj < seg) off += tot[jj][lw];
                float run = off;
                #pragma unroll
                for (int k = 0; k < SEGLEN; ++k) { run += v[k]; ii[(h0 + k) * IW + col] = run; }
            }
            LGKM_BAR();
        }
        // ---- W cumsum: b128 float4 segments, register carry ----
        {
            float4 q0, q1, q2, q3;
            int row = lw, w0 = seg * SEGLEN;
            float4* rp = (float4*)&ii[row * IW + w0];
            if (act) {
                q0 = rp[0]; q1 = rp[1]; q2 = rp[2]; q3 = rp[3];
                float s;
                s  = q0.x; s += q0.y; s += q0.z; s += q0.w;
                s += q1.x; s += q1.y; s += q1.z; s += q1.w;
                s += q2.x; s += q2.y; s += q2.z; s += q2.w;
                s += q3.x; s += q3.y; s += q3.z; s += q3.w;
                tot[seg][row] = s;
            }
            LGKM_BAR();
            if (act) {
                float off = 0.0f;
                #pragma unroll
                for (int jj = 0; jj < NSEG - 1; ++jj) if (jj < seg) off += tot[jj][row];
                float run = off;
                run += q0.x; q0.x = run; run += q0.y; q0.y = run;
                run += q0.z; q0.z = run; run += q0.w; q0.w = run;
                run += q1.x; q1.x = run; run += q1.y; q1.y = run;
                run += q1.z; q1.z = run; run += q1.w; q1.w = run;
                run += q2.x; q2.x = run; run += q2.y; q2.y = run;
                run += q2.z; q2.z = run; run += q2.w; q2.w = run;
                run += q3.x; q3.x = run; run += q3.y; q3.y = run;
                run += q3.z; q3.z = run; run += q3.w; q3.w = run;
                rp[0] = q0; rp[1] = q1; rp[2] = q2; rp[3] = q3;
            }
            LGKM_BAR();
        }

        // ---- hot: guarded II lookups (II(h,w)=ii[h-1][w-1], 0 if h==0||w==0) ----
        #define IIV(hq, wq) ( ((hq) > 0 && (wq) > 0)                              \
            ? ii[((hq) - 1) * IW + ((wq) - 1)] : 0.0f )
        #define EMIT(jX, hX, wX)                                                  \
        if (jX < j1) {                                                            \
            int hs = hX & 255, he = (int)(hX >> 8);                               \
            int ws = wX & 255, we = (int)(wX >> 8);                               \
            float s = ((IIV(he, we) - IIV(hs, we))                                \
                     -  IIV(he, ws)) + IIV(hs, ws);                               \
            int area = (he - hs) * (we - ws);                                     \
            dst[(size_t)c * R + jX] = (area > 0) ? (s / (float)area) : 0.0f;      \
        }
        EMIT(jA, hA, wA)
        EMIT(jB, hB, wB)
        EMIT(jC, hC, wC)
        EMIT(jD, hD, wD)
        #undef EMIT
        #undef IIV

        LGKM_BAR();   // hot reads of ii drained before next stage overwrites it
    }
}

// ---------- transpose: ws_T[1029][R](j-indexed) -> out[R][1029] -------------
__global__ __launch_bounds__(256) void transpose_kernel(
    const float* __restrict__ in, const int* __restrict__ jlist,
    float* __restrict__ out, int R, int C)
{
    __shared__ float t[64][65];
    __shared__ int rows[64];
    int j0 = blockIdx.x * 64;
    int c0 = blockIdx.y * 64;
    int tx = threadIdx.x, ty = threadIdx.y;
    int tid = ty * 64 + tx;

    if (tid < 64 && j0 + tid < R) rows[tid] = jlist[j0 + tid];

    #pragma unroll
    for (int k0 = 0; k0 < 64; k0 += 4) {
        int k = k0 + ty;
        int cc = c0 + k, jj = j0 + tx;
        if (cc < C && jj < R) t[k][tx] = in[(size_t)cc * R + jj];
    }
    __syncthreads();
    #pragma unroll
    for (int k0 = 0; k0 < 64; k0 += 4) {
        int k = k0 + ty;
        int cc = c0 + tx;
        if (j0 + k < R && cc < C) out[(size_t)rows[k] * C + cc] = t[tx][k];
    }
}

// ---------- fallback: correctness-only direct path (ws too small) -----------
__global__ __launch_bounds__(256) void psroi_fallback_kernel(
    const float* __restrict__ feat, const float* __restrict__ rois,
    int R, float* __restrict__ out)
{
    __shared__ float ii[81 * 81];
    int bid = blockIdx.x;
    int b = bid / CC, c = bid % CC;
    int rem = c % 49, gh = rem / 7, gw = rem % 7;

    const float* plane = feat + ((size_t)b * CC + c) * PLANE;
    for (int i = threadIdx.x; i < PLANE; i += 256) {
        int h = i / WW, w = i % WW;
        ii[(h + 1) * 81 + (w + 1)] = plane[i];
    }
    for (int i = threadIdx.x; i < 81; i += 256) { ii[i] = 0.0f; ii[i * 81] = 0.0f; }
    __syncthreads();
    if (threadIdx.x < WW) {
        int w = threadIdx.x + 1; float s = 0.0f;
        for (int h = 1; h <= HH; ++h) { s += ii[h * 81 + w]; ii[h * 81 + w] = s; }
    }
    __syncthreads();
    if (threadIdx.x < HH) {
        int h = threadIdx.x + 1; float* row = &ii[h * 81]; float s = 0.0f;
        for (int w = 1; w <= WW; ++w) { s += row[w]; row[w] = s; }
    }
    __syncthreads();
    for (int r = threadIdx.x; r < R; r += 256) {
        const float* roi = rois + (size_t)r * 5;
        if ((int)roi[0] != b) continue;
        float x1 = rintf(roi[1]) * 0.0625f;
        float y1 = rintf(roi[2]) * 0.0625f;
        float x2 = (rintf(roi[3]) + 1.0f) * 0.0625f;
        float y2 = (rintf(roi[4]) + 1.0f) * 0.0625f;
        float bw = fmaxf(x2 - x1, 0.1f) * recip7();
        float bh = fmaxf(y2 - y1, 0.1f) * recip7();
        asm volatile("" : "+v"(bw), "+v"(bh));
        int hs = (int)fminf(fmaxf(floorf(mul_add_nofma((float)gh,     bh, y1)), 0.0f), 80.0f);
        int he = (int)fminf(fmaxf(ceilf (mul_add_nofma((float)(gh+1), bh, y1)), 0.0f), 80.0f);
        int ws = (int)fminf(fmaxf(floorf(mul_add_nofma((float)gw,     bw, x1)), 0.0f), 80.0f);
        int we = (int)fminf(fmaxf(ceilf (mul_add_nofma((float)(gw+1), bw, x1)), 0.0f), 80.0f);
        float s = ii[he * 81 + we] - ii[hs * 81 + we] - ii[he * 81 + ws] + ii[hs * 81 + ws];
        int area = (he - hs) * (we - ws);
        out[(size_t)r * CC + c] = (area > 0) ? (s / (float)area) : 0.0f;
    }
}

extern "C" void kernel_launch(void* const* d_in, const int* in_sizes, int n_in,
                              void* d_out, int out_size, void* d_ws, size_t ws_size,
                              hipStream_t stream)
{
    const float* feat = (const float*)d_in[0];
    const float* rois = (const float*)d_in[1];
    float* out        = (float*)d_out;

    int R = in_sizes[1] / 5;
    int N = in_sizes[0] / (CC * PLANE);
    int NPLANES = N * CC;

    size_t off_wsT  = 0;
    size_t off_hshe = (off_wsT + (size_t)CC * R * sizeof(float) + 15) & ~(size_t)15;
    size_t off_wswe = off_hshe + (size_t)R * 7 * sizeof(unsigned short);
    size_t off_jl   = (off_wswe + (size_t)R * 7 * sizeof(unsigned short) + 15) & ~(size_t)15;
    size_t off_base = off_jl + (size_t)R * sizeof(int);
    size_t need     = off_base + (size_t)(N + 1) * sizeof(int);

    bool chunk_ok = (((R + 15) / 16) % 64) == 0;

    if (ws_size >= need && N <= 8 && R <= 2048 && chunk_ok && NPLANES > NBLK) {
        char* ws = (char*)d_ws;
        float*          ws_T = (float*)(ws + off_wsT);
        unsigned short* hshe = (unsigned short*)(ws + off_hshe);
        unsigned short* wswe = (unsigned short*)(ws + off_wswe);
        int*            jl   = (int*)(ws + off_jl);
        int*            base = (int*)(ws + off_base);

        prep_kernel<<<1, 1024, 0, stream>>>(rois, R, N, hshe, wswe, jl, base);
        psroi_plane_kernel<<<NBLK, 512, 0, stream>>>(
            feat, R, NPLANES, hshe, wswe, jl, base, ws_T);
        dim3 blk(64, 4), grd((R + 63) / 64, (CC + 63) / 64);
        transpose_kernel<<<grd, blk, 0, stream>>>(ws_T, jl, out, R, CC);
    } else {
        psroi_fallback_kernel<<<NPLANES, 256, 0, stream>>>(feat, rois, R, out);
    }
}